// Round 1
// baseline (183.016 us; speedup 1.0000x reference)
//
#include <hip/hip_runtime.h>

#define B 16
#define S 2048
#define VOCAB 32000
#define D_EMB 256
#define D_MODEL 512
#define LN_EPS 1e-5f

// ---------------------------------------------------------------------------
// Kernel A: Wk[b][m][i] = sum_j Wb[m,i,j] * king_table[kid[b], j]
// grid = 512 (one block per m), 256 threads (one per i)
// ---------------------------------------------------------------------------
__global__ __launch_bounds__(256) void wk_kernel(
    const float* __restrict__ Wb,
    const float* __restrict__ king_table,
    const int* __restrict__ king_id,
    float* __restrict__ Wk)
{
    __shared__ float wT[64][257];   // transposed chunk: wT[jj][i], +1 pad
    const int m = blockIdx.x;
    const int i = threadIdx.x;

    int kid[B];
#pragma unroll
    for (int b = 0; b < B; ++b) kid[b] = king_id[b];   // uniform -> SGPR

    float acc[B];
#pragma unroll
    for (int b = 0; b < B; ++b) acc[b] = 0.0f;

    const float* wrow = Wb + (size_t)m * (D_EMB * D_EMB);

    for (int j0 = 0; j0 < D_EMB; j0 += 64) {
        __syncthreads();
        // cooperative coalesced load of Wb[m][:, j0:j0+64] -> transposed LDS
        // 256 rows x 16 float4 each = 4096 float4, 256 threads x 16 iters
#pragma unroll
        for (int it = 0; it < 16; ++it) {
            int idx = it * 256 + i;
            int row = idx >> 4;       // i index [0,256)
            int c4  = idx & 15;       // which float4 within 64-wide chunk
            float4 v = *(const float4*)(wrow + row * D_EMB + j0 + c4 * 4);
            wT[c4 * 4 + 0][row] = v.x;
            wT[c4 * 4 + 1][row] = v.y;
            wT[c4 * 4 + 2][row] = v.z;
            wT[c4 * 4 + 3][row] = v.w;
        }
        __syncthreads();

#pragma unroll
        for (int jj4 = 0; jj4 < 16; ++jj4) {
            float w0 = wT[jj4 * 4 + 0][i];
            float w1 = wT[jj4 * 4 + 1][i];
            float w2 = wT[jj4 * 4 + 2][i];
            float w3 = wT[jj4 * 4 + 3][i];
            int j = j0 + jj4 * 4;
#pragma unroll
            for (int b = 0; b < B; ++b) {
                const float* kp = king_table + (size_t)kid[b] * D_EMB + j;
                float k0 = kp[0], k1 = kp[1], k2 = kp[2], k3 = kp[3];
                acc[b] = fmaf(w0, k0, acc[b]);
                acc[b] = fmaf(w1, k1, acc[b]);
                acc[b] = fmaf(w2, k2, acc[b]);
                acc[b] = fmaf(w3, k3, acc[b]);
            }
        }
    }

#pragma unroll
    for (int b = 0; b < B; ++b)
        Wk[((size_t)b * D_MODEL + m) * D_EMB + i] = acc[b];
}

// ---------------------------------------------------------------------------
// Kernel B: x[b,s,m] = sum_i tok[b,s,i]*Wk[b,m,i] + bb[m]; LayerNorm over m.
// grid = (S/64, B), 512 threads. Per-block tile: 64 s-rows x 512 m-cols.
// Thread (ty in [0,16), tx in [0,32)): 4 s-rows (ty*4+r), 16 m-cols
// (m = c4*128 + tx*4 + cc) -> coalesced float4 stores.
// ---------------------------------------------------------------------------
#define TS 64
#define JC 16

__global__ __launch_bounds__(512) void gemm_ln_kernel(
    const int* __restrict__ seq,
    const int* __restrict__ king_id,
    const float* __restrict__ token_tables,
    const float* __restrict__ Wk,
    const float* __restrict__ bb,
    const float* __restrict__ gamma,
    const float* __restrict__ beta,
    float* __restrict__ out)
{
    __shared__ float tokT[JC][TS + 1];        // [16][65]
    __shared__ float wkT[JC][D_MODEL + 4];    // [16][516]
    __shared__ int   seq_lds[TS];

    const int b  = blockIdx.y;
    const int s0 = blockIdx.x * TS;
    const int t  = threadIdx.x;
    const int tx = t & 31;    // m partition (32 lanes)
    const int ty = t >> 5;    // s partition (16 groups of 4 rows)

    const int kb = king_id[b];

    if (t < TS) seq_lds[t] = seq[b * S + s0 + t];

    float acc[4][16];
#pragma unroll
    for (int r = 0; r < 4; ++r)
#pragma unroll
        for (int k = 0; k < 16; ++k) acc[r][k] = 0.0f;

    const float* ttab = token_tables + (size_t)kb * VOCAB * D_EMB;
    const float* wkb  = Wk + (size_t)b * D_MODEL * D_EMB;

    for (int j0 = 0; j0 < D_EMB; j0 += JC) {
        __syncthreads();   // guard LDS reuse (also covers seq_lds on iter 0)

        // ---- stage tok tile (gather): 64 rows x 16 floats, transposed ----
        if (t < 256) {
            int sl = t >> 2;           // [0,64)
            int c4 = t & 3;            // [0,4)
            const float* rp = ttab + (size_t)seq_lds[sl] * D_EMB + j0 + c4 * 4;
            float4 v = *(const float4*)rp;
            tokT[c4 * 4 + 0][sl] = v.x;
            tokT[c4 * 4 + 1][sl] = v.y;
            tokT[c4 * 4 + 2][sl] = v.z;
            tokT[c4 * 4 + 3][sl] = v.w;
        }
        // ---- stage Wk tile: 512 rows x 16 floats, transposed ----
#pragma unroll
        for (int it = 0; it < 4; ++it) {
            int idx = it * 512 + t;
            int mr  = idx >> 2;        // [0,512)
            int c4  = idx & 3;
            float4 v = *(const float4*)(wkb + (size_t)mr * D_EMB + j0 + c4 * 4);
            wkT[c4 * 4 + 0][mr] = v.x;
            wkT[c4 * 4 + 1][mr] = v.y;
            wkT[c4 * 4 + 2][mr] = v.z;
            wkT[c4 * 4 + 3][mr] = v.w;
        }
        __syncthreads();

        // ---- register-tiled outer product ----
#pragma unroll
        for (int jj = 0; jj < JC; ++jj) {
            float tv[4];
#pragma unroll
            for (int r = 0; r < 4; ++r) tv[r] = tokT[jj][ty * 4 + r];
            float4 wv[4];
#pragma unroll
            for (int c4 = 0; c4 < 4; ++c4)
                wv[c4] = *(const float4*)&wkT[jj][c4 * 128 + tx * 4];
#pragma unroll
            for (int r = 0; r < 4; ++r) {
#pragma unroll
                for (int c4 = 0; c4 < 4; ++c4) {
                    acc[r][c4 * 4 + 0] = fmaf(tv[r], wv[c4].x, acc[r][c4 * 4 + 0]);
                    acc[r][c4 * 4 + 1] = fmaf(tv[r], wv[c4].y, acc[r][c4 * 4 + 1]);
                    acc[r][c4 * 4 + 2] = fmaf(tv[r], wv[c4].z, acc[r][c4 * 4 + 2]);
                    acc[r][c4 * 4 + 3] = fmaf(tv[r], wv[c4].w, acc[r][c4 * 4 + 3]);
                }
            }
        }
    }

    // ---- epilogue: + bb, LayerNorm over m (512 = 32 lanes x 16/thread) ----
    float bbv[16], gv[16], bv[16];
#pragma unroll
    for (int c4 = 0; c4 < 4; ++c4) {
        float4 vb = *(const float4*)(bb    + c4 * 128 + tx * 4);
        float4 vg = *(const float4*)(gamma + c4 * 128 + tx * 4);
        float4 ve = *(const float4*)(beta  + c4 * 128 + tx * 4);
        bbv[c4 * 4 + 0] = vb.x; bbv[c4 * 4 + 1] = vb.y; bbv[c4 * 4 + 2] = vb.z; bbv[c4 * 4 + 3] = vb.w;
        gv[c4 * 4 + 0]  = vg.x; gv[c4 * 4 + 1]  = vg.y; gv[c4 * 4 + 2]  = vg.z; gv[c4 * 4 + 3]  = vg.w;
        bv[c4 * 4 + 0]  = ve.x; bv[c4 * 4 + 1]  = ve.y; bv[c4 * 4 + 2]  = ve.z; bv[c4 * 4 + 3]  = ve.w;
    }

#pragma unroll
    for (int r = 0; r < 4; ++r) {
        float s1 = 0.0f;
#pragma unroll
        for (int k = 0; k < 16; ++k) {
            acc[r][k] += bbv[k];
            s1 += acc[r][k];
        }
#pragma unroll
        for (int off = 1; off < 32; off <<= 1) s1 += __shfl_xor(s1, off);
        float mean = s1 * (1.0f / D_MODEL);

        float s2 = 0.0f;
#pragma unroll
        for (int k = 0; k < 16; ++k) {
            float d = acc[r][k] - mean;
            s2 += d * d;
        }
#pragma unroll
        for (int off = 1; off < 32; off <<= 1) s2 += __shfl_xor(s2, off);
        float inv = rsqrtf(s2 * (1.0f / D_MODEL) + LN_EPS);

        int s = s0 + ty * 4 + r;
        float* op = out + ((size_t)b * S + s) * D_MODEL;
#pragma unroll
        for (int c4 = 0; c4 < 4; ++c4) {
            float4 o;
            o.x = (acc[r][c4 * 4 + 0] - mean) * inv * gv[c4 * 4 + 0] + bv[c4 * 4 + 0];
            o.y = (acc[r][c4 * 4 + 1] - mean) * inv * gv[c4 * 4 + 1] + bv[c4 * 4 + 1];
            o.z = (acc[r][c4 * 4 + 2] - mean) * inv * gv[c4 * 4 + 2] + bv[c4 * 4 + 2];
            o.w = (acc[r][c4 * 4 + 3] - mean) * inv * gv[c4 * 4 + 3] + bv[c4 * 4 + 3];
            *(float4*)(op + c4 * 128 + tx * 4) = o;
        }
    }
}

// ---------------------------------------------------------------------------
extern "C" void kernel_launch(void* const* d_in, const int* in_sizes, int n_in,
                              void* d_out, int out_size, void* d_ws, size_t ws_size,
                              hipStream_t stream)
{
    const int*   seq          = (const int*)d_in[0];
    const int*   king_id      = (const int*)d_in[1];
    const float* token_tables = (const float*)d_in[2];
    const float* Wb           = (const float*)d_in[3];
    const float* bb           = (const float*)d_in[4];
    const float* king_table   = (const float*)d_in[5];
    const float* gamma        = (const float*)d_in[6];
    const float* beta         = (const float*)d_in[7];
    float* out = (float*)d_out;

    float* Wk = (float*)d_ws;   // B * D_MODEL * D_EMB fp32 = 8 MB

    wk_kernel<<<dim3(D_MODEL), dim3(256), 0, stream>>>(Wb, king_table, king_id, Wk);
    gemm_ln_kernel<<<dim3(S / TS, B), dim3(512), 0, stream>>>(
        seq, king_id, token_tables, Wk, bb, gamma, beta, out);
}

// Round 2
// 103.694 us; speedup vs baseline: 1.7650x; 1.7650x over previous
//
#include <hip/hip_runtime.h>
#include <hip/hip_bf16.h>

#define B 16
#define S 2048
#define VOCAB 32000
#define D_EMB 256
#define D_MODEL 512
#define LN_EPS 1e-5f

using bf16x8 = __attribute__((ext_vector_type(8))) short;
using f32x4  = __attribute__((ext_vector_type(4))) float;

static __device__ __forceinline__ unsigned short f2bf(float f) {
    __hip_bfloat16 h = __float2bfloat16(f);   // RNE
    return *reinterpret_cast<unsigned short*>(&h);
}

// ---------------------------------------------------------------------------
// Kernel A: Wk_bf16[b][m][k] = sum_j Wb[m,k,j] * king_table[kid[b], j]
// grid = 512 (one block per m), 256 threads (one per k a.k.a. i)
// Output layout [b][m][k] row-major bf16 == the MFMA B^T fragment layout.
// ---------------------------------------------------------------------------
__global__ __launch_bounds__(256) void wk_kernel(
    const float* __restrict__ Wb,
    const float* __restrict__ king_table,
    const int* __restrict__ king_id,
    unsigned short* __restrict__ Wk)
{
    __shared__ float wT[64][257];   // transposed chunk: wT[jj][i], +1 pad
    const int m = blockIdx.x;
    const int i = threadIdx.x;

    int kid[B];
#pragma unroll
    for (int b = 0; b < B; ++b) kid[b] = king_id[b];   // uniform -> SGPR

    float acc[B];
#pragma unroll
    for (int b = 0; b < B; ++b) acc[b] = 0.0f;

    const float* wrow = Wb + (size_t)m * (D_EMB * D_EMB);

    for (int j0 = 0; j0 < D_EMB; j0 += 64) {
        __syncthreads();
        // coalesced load of Wb[m][:, j0:j0+64] -> transposed LDS
#pragma unroll
        for (int it = 0; it < 16; ++it) {
            int idx = it * 256 + i;
            int row = idx >> 4;       // i index [0,256)
            int c4  = idx & 15;       // which float4 within 64-wide chunk
            float4 v = *(const float4*)(wrow + row * D_EMB + j0 + c4 * 4);
            wT[c4 * 4 + 0][row] = v.x;
            wT[c4 * 4 + 1][row] = v.y;
            wT[c4 * 4 + 2][row] = v.z;
            wT[c4 * 4 + 3][row] = v.w;
        }
        __syncthreads();

#pragma unroll
        for (int jj4 = 0; jj4 < 16; ++jj4) {
            float w0 = wT[jj4 * 4 + 0][i];
            float w1 = wT[jj4 * 4 + 1][i];
            float w2 = wT[jj4 * 4 + 2][i];
            float w3 = wT[jj4 * 4 + 3][i];
            int j = j0 + jj4 * 4;
#pragma unroll
            for (int b = 0; b < B; ++b) {
                const float* kp = king_table + (size_t)kid[b] * D_EMB + j;
                acc[b] = fmaf(w0, kp[0], acc[b]);
                acc[b] = fmaf(w1, kp[1], acc[b]);
                acc[b] = fmaf(w2, kp[2], acc[b]);
                acc[b] = fmaf(w3, kp[3], acc[b]);
            }
        }
    }

#pragma unroll
    for (int b = 0; b < B; ++b)
        Wk[((size_t)b * D_MODEL + m) * D_EMB + i] = f2bf(acc[b]);
}

// ---------------------------------------------------------------------------
// Kernel B (MFMA): x[b,s,m] = sum_k tok[b,s,k]*Wk[b,m,k] + bb[m]; LN over m.
// grid = (S/64, B), 512 threads = 8 waves.
// Block tile: 64 s-rows x 512 m-cols (full m-span -> LN is block-local).
// Wave w owns m-slice [w*64, w*64+64): M_rep=4 (16-row frags), N_rep=4.
// A (tok) staged once in LDS as bf16 [64][264]; B (Wk bf16) direct global.
// mfma_f32_16x16x32_bf16 frag layout: A/B lane l -> row/col = l&15,
// k = (l>>4)*8 + j (16B contiguous). C/D: col = l&15, row = (l>>4)*4 + reg.
// ---------------------------------------------------------------------------
#define TSB 64

__global__ __launch_bounds__(512) void gemm_ln_mfma(
    const int* __restrict__ seq,
    const int* __restrict__ king_id,
    const float* __restrict__ token_tables,
    const unsigned short* __restrict__ Wk,
    const float* __restrict__ bb,
    const float* __restrict__ gamma,
    const float* __restrict__ beta,
    float* __restrict__ out)
{
    __shared__ unsigned short tokL[TSB][264];   // 64 x (256+8 pad) bf16 = 33 KB
    __shared__ float red_sum[8][TSB];
    __shared__ float red_sq[8][TSB];
    __shared__ float stats[2][TSB];             // [0]=mean, [1]=rstd

    const int b    = blockIdx.y;
    const int s0   = blockIdx.x * TSB;
    const int t    = threadIdx.x;
    const int lane = t & 63;
    const int wave = t >> 6;
    const int lr   = lane & 15;     // frag row/col index
    const int kg   = lane >> 4;     // k-group (0..3)

    const int kb = king_id[b];
    const float* ttab = token_tables + (size_t)kb * VOCAB * D_EMB;

    // ---- stage gathered tok tile: fp32 global -> bf16 LDS ----
    {
        int row = t >> 3;            // 0..63
        int ck  = (t & 7) * 32;      // k chunk start (32 floats)
        int tokidx = seq[b * S + s0 + row];
        const float4* src = (const float4*)(ttab + (size_t)tokidx * D_EMB + ck);
#pragma unroll
        for (int u = 0; u < 4; ++u) {
            float4 v0 = src[u * 2 + 0];
            float4 v1 = src[u * 2 + 1];
            union { unsigned short us[8]; uint4 q; } pk;
            pk.us[0] = f2bf(v0.x); pk.us[1] = f2bf(v0.y);
            pk.us[2] = f2bf(v0.z); pk.us[3] = f2bf(v0.w);
            pk.us[4] = f2bf(v1.x); pk.us[5] = f2bf(v1.y);
            pk.us[6] = f2bf(v1.z); pk.us[7] = f2bf(v1.w);
            *(uint4*)&tokL[row][ck + u * 8] = pk.q;
        }
    }
    __syncthreads();

    // ---- fragment pointers ----
    const int m0 = wave * 64;                  // wave's m-slice base
    const uint4* aptr[4];
    const uint4* bptr[4];
#pragma unroll
    for (int mf = 0; mf < 4; ++mf)
        aptr[mf] = (const uint4*)&tokL[mf * 16 + lr][kg * 8];
#pragma unroll
    for (int nf = 0; nf < 4; ++nf) {
        int col = m0 + nf * 16 + lr;
        bptr[nf] = (const uint4*)(Wk + ((size_t)(b * D_MODEL + col)) * D_EMB + kg * 8);
    }

    f32x4 acc[4][4] = {};

    // ---- K loop: 8 steps of K=32, fully unrolled ----
#pragma unroll
    for (int step = 0; step < 8; ++step) {
        bf16x8 af[4], bfr[4];
#pragma unroll
        for (int mf = 0; mf < 4; ++mf) {
            uint4 q = aptr[mf][step * 4];
            af[mf] = __builtin_bit_cast(bf16x8, q);
        }
#pragma unroll
        for (int nf = 0; nf < 4; ++nf) {
            uint4 q = bptr[nf][step * 4];
            bfr[nf] = __builtin_bit_cast(bf16x8, q);
        }
#pragma unroll
        for (int mf = 0; mf < 4; ++mf)
#pragma unroll
            for (int nf = 0; nf < 4; ++nf)
                acc[mf][nf] = __builtin_amdgcn_mfma_f32_16x16x32_bf16(
                    af[mf], bfr[nf], acc[mf][nf], 0, 0, 0);
    }

    // ---- epilogue: bias, block-wide LN stats ----
    float bbv[4], gv[4], bv[4];
#pragma unroll
    for (int nf = 0; nf < 4; ++nf) {
        int col = m0 + nf * 16 + lr;
        bbv[nf] = bb[col];
        gv[nf]  = gamma[col];
        bv[nf]  = beta[col];
    }

#pragma unroll
    for (int mf = 0; mf < 4; ++mf) {
#pragma unroll
        for (int r = 0; r < 4; ++r) {
            float sum = 0.0f, sq = 0.0f;
#pragma unroll
            for (int nf = 0; nf < 4; ++nf) {
                float v = acc[mf][nf][r] + bbv[nf];
                acc[mf][nf][r] = v;
                sum += v;
                sq  += v * v;
            }
#pragma unroll
            for (int off = 1; off < 16; off <<= 1) {
                sum += __shfl_xor(sum, off);
                sq  += __shfl_xor(sq, off);
            }
            if (lr == 0) {
                int row = mf * 16 + kg * 4 + r;
                red_sum[wave][row] = sum;
                red_sq[wave][row]  = sq;
            }
        }
    }
    __syncthreads();

    if (t < TSB) {
        float s = 0.0f, q = 0.0f;
#pragma unroll
        for (int w = 0; w < 8; ++w) { s += red_sum[w][t]; q += red_sq[w][t]; }
        float mean = s * (1.0f / D_MODEL);
        float var  = q * (1.0f / D_MODEL) - mean * mean;
        stats[0][t] = mean;
        stats[1][t] = rsqrtf(var + LN_EPS);
    }
    __syncthreads();

    // ---- normalize + store ----
#pragma unroll
    for (int mf = 0; mf < 4; ++mf) {
#pragma unroll
        for (int r = 0; r < 4; ++r) {
            int row = mf * 16 + kg * 4 + r;
            float mean = stats[0][row];
            float rstd = stats[1][row];
            float* op = out + ((size_t)b * S + s0 + row) * D_MODEL + m0 + lr;
#pragma unroll
            for (int nf = 0; nf < 4; ++nf)
                op[nf * 16] = (acc[mf][nf][r] - mean) * rstd * gv[nf] + bv[nf];
        }
    }
}

// ---------------------------------------------------------------------------
extern "C" void kernel_launch(void* const* d_in, const int* in_sizes, int n_in,
                              void* d_out, int out_size, void* d_ws, size_t ws_size,
                              hipStream_t stream)
{
    const int*   seq          = (const int*)d_in[0];
    const int*   king_id      = (const int*)d_in[1];
    const float* token_tables = (const float*)d_in[2];
    const float* Wb           = (const float*)d_in[3];
    const float* bb           = (const float*)d_in[4];
    const float* king_table   = (const float*)d_in[5];
    const float* gamma        = (const float*)d_in[6];
    const float* beta         = (const float*)d_in[7];
    float* out = (float*)d_out;

    unsigned short* Wk = (unsigned short*)d_ws;   // B*D_MODEL*D_EMB bf16 = 4 MB

    wk_kernel<<<dim3(D_MODEL), dim3(256), 0, stream>>>(Wb, king_table, king_id, Wk);
    gemm_ln_mfma<<<dim3(S / TSB, B), dim3(512), 0, stream>>>(
        seq, king_id, token_tables, Wk, bb, gamma, beta, out);
}